// Round 5
// baseline (478.763 us; speedup 1.0000x reference)
//
#include <hip/hip_runtime.h>
#include <hip/hip_bf16.h>
#include <cstdint>

#define ASPACE(n) __attribute__((address_space(n)))

typedef short bf16x8 __attribute__((ext_vector_type(8)));
typedef float f32x4 __attribute__((ext_vector_type(4)));

__device__ __forceinline__ unsigned short f2bf(float f) {
  uint32_t u = __float_as_uint(f);
  u += 0x7fffu + ((u >> 16) & 1u);
  return (unsigned short)(u >> 16);
}
__device__ __forceinline__ float bf2f(unsigned short h) {
  return __uint_as_float(((uint32_t)h) << 16);
}

// ---------------- fp32 -> bf16 conversion ----------------
__global__ __launch_bounds__(256) void conv_f32_bf16(const float4* __restrict__ src,
                                                     ushort4* __restrict__ dst, int n4) {
  int i = blockIdx.x * blockDim.x + threadIdx.x;
  int stride = gridDim.x * blockDim.x;
  for (; i < n4; i += stride) {
    float4 v = src[i];
    ushort4 o;
    o.x = f2bf(v.x); o.y = f2bf(v.y); o.z = f2bf(v.z); o.w = f2bf(v.w);
    dst[i] = o;
  }
}

// ---------------- bf16 GEMM (B^T input): C[m,n] = sum_k A[m,k]*B[n,k] ----------------
// BM=256, BN=128, BK=64, 512 threads (8 waves as 4x2, per-wave 64x64 output).
// 3 LDS buffers (144 KiB), 2-tiles-ahead prefetch, counted vmcnt (never 0 in steady
// state; tail drains 12->6->0). T2 swizzle chunk ^= row&7 on both stage-source and read.

__device__ __forceinline__ void gload16(const unsigned short* g, unsigned short* l) {
  __builtin_amdgcn_global_load_lds((const ASPACE(1) void*)g, (ASPACE(3) void*)l, 16, 0, 0);
}

// A-tile: 256x64 bf16 = 2048 16B-chunks; 512 threads -> 4 gloads each.
__device__ __forceinline__ void stage_A(const unsigned short* __restrict__ gbase, int K, int k0,
                                        unsigned short* lds, int wave, int tid) {
#pragma unroll
  for (int i = 0; i < 4; ++i) {
    const int c = i * 512 + tid;
    const int r = c >> 3;
    const int gc = (c & 7) ^ (r & 7);           // involutive swizzle on source
    gload16(gbase + (size_t)r * K + k0 + gc * 8, lds + (i * 512 + wave * 64) * 8);
  }
}
// B-tile: 128x64 = 1024 chunks; 2 gloads each.
__device__ __forceinline__ void stage_B(const unsigned short* __restrict__ gbase, int K, int k0,
                                        unsigned short* lds, int wave, int tid) {
#pragma unroll
  for (int i = 0; i < 2; ++i) {
    const int c = i * 512 + tid;
    const int r = c >> 3;
    const int gc = (c & 7) ^ (r & 7);
    gload16(gbase + (size_t)r * K + k0 + gc * 8, lds + (i * 512 + wave * 64) * 8);
  }
}

// fragment read: logical (row, chunk cb) -> physical chunk cb ^ (row&7); row stride 64
__device__ __forceinline__ bf16x8 frag_ld(const unsigned short* S, int row, int cb) {
  return *(const bf16x8*)(S + row * 64 + ((cb ^ (row & 7)) * 8));
}

// OUT_MODE 0: bf16 out, no bias.  OUT_MODE 1: fp32 out + bias.
template <int OUT_MODE>
__global__ __launch_bounds__(512, 2) void gemm_bt(const unsigned short* __restrict__ A,
                                                  const unsigned short* __restrict__ B,
                                                  void* __restrict__ Cout,
                                                  const float* __restrict__ bias,
                                                  int M, int N, int K) {
  __shared__ unsigned short As[3][256 * 64];   // 96 KiB
  __shared__ unsigned short Bs[3][128 * 64];   // 48 KiB

  const int tid  = threadIdx.x;
  const int lane = tid & 63;
  const int wave = tid >> 6;
  const int wr = wave >> 1;        // 0..3  -> 64-row band of the 256-row tile
  const int wc = wave & 1;         // 0..1  -> 64-col band of the 128-col tile

  // 1D grid: XCD-chunked (nwg % 8 == 0), N-tile fastest for A L2-reuse
  const int nwg = gridDim.x;
  const int swz = (blockIdx.x & 7) * (nwg >> 3) + (blockIdx.x >> 3);
  const int ntn = N >> 7;
  const int bn0 = (swz % ntn) << 7;
  const int bm0 = (swz / ntn) << 8;

  const unsigned short* Abase = A + (size_t)bm0 * K;
  const unsigned short* Bbase = B + (size_t)bn0 * K;

  f32x4 acc[4][4];
#pragma unroll
  for (int m = 0; m < 4; ++m)
#pragma unroll
    for (int n = 0; n < 4; ++n) {
      f32x4 z = {0.f, 0.f, 0.f, 0.f};
      acc[m][n] = z;
    }

  const int fr = lane & 15;
  const int hi = lane >> 4;
  const int T = K >> 6;            // 6 for K=384

  // prologue: stage tiles 0,1,2 into bufs 0,1,2 (18 loads/thread total)
  stage_A(Abase, K, 0, As[0], wave, tid);
  stage_B(Bbase, K, 0, Bs[0], wave, tid);
  if (T > 1) { stage_A(Abase, K, 64, As[1], wave, tid); stage_B(Bbase, K, 64, Bs[1], wave, tid); }
  if (T > 2) { stage_A(Abase, K, 128, As[2], wave, tid); stage_B(Bbase, K, 128, Bs[2], wave, tid); }

  int cur = 0;
  for (int t = 0; t < T; ++t) {
    // wait for tile t's 6 loads: outstanding after them = 6 * min(2, T-1-t)
    if (t + 2 < T)      asm volatile("s_waitcnt vmcnt(12)" ::: "memory");
    else if (t + 1 < T) asm volatile("s_waitcnt vmcnt(6)"  ::: "memory");
    else                asm volatile("s_waitcnt vmcnt(0)"  ::: "memory");
    __builtin_amdgcn_s_barrier();          // publish: tile t visible to all waves
    asm volatile("" ::: "memory");

    const unsigned short* Ab = As[cur];
    const unsigned short* Bb = Bs[cur];
#pragma unroll
    for (int ks = 0; ks < 2; ++ks) {
      bf16x8 af[4], bfv[4];
      const int cb = ks * 4 + hi;
#pragma unroll
      for (int m = 0; m < 4; ++m) af[m] = frag_ld(Ab, wr * 64 + m * 16 + fr, cb);
#pragma unroll
      for (int n = 0; n < 4; ++n) bfv[n] = frag_ld(Bb, wc * 64 + n * 16 + fr, cb);
#pragma unroll
      for (int m = 0; m < 4; ++m)
#pragma unroll
        for (int n = 0; n < 4; ++n)
          acc[m][n] = __builtin_amdgcn_mfma_f32_16x16x32_bf16(af[m], bfv[n], acc[m][n], 0, 0, 0);
    }

    asm volatile("" ::: "memory");
    __builtin_amdgcn_s_barrier();          // all waves done reading buf[cur]
    asm volatile("" ::: "memory");
    if (t + 3 < T) {                       // refill the vacated buffer with tile t+3
      stage_A(Abase, K, (t + 3) << 6, As[cur], wave, tid);
      stage_B(Bbase, K, (t + 3) << 6, Bs[cur], wave, tid);
    }
    cur = (cur == 2) ? 0 : cur + 1;
  }

  // epilogue: C/D layout col = lane&15, row = (lane>>4)*4 + reg   [guide-verified m89/m91]
  const int rq = hi * 4;
  if (OUT_MODE == 1) {
    float* C = (float*)Cout;
#pragma unroll
    for (int m = 0; m < 4; ++m) {
#pragma unroll
      for (int n = 0; n < 4; ++n) {
        int col = bn0 + wc * 64 + n * 16 + fr;
        float bv = bias[col];
#pragma unroll
        for (int r = 0; r < 4; ++r) {
          int row = bm0 + wr * 64 + m * 16 + rq + r;
          C[(size_t)row * N + col] = acc[m][n][r] + bv;
        }
      }
    }
  } else {
    unsigned short* C = (unsigned short*)Cout;
#pragma unroll
    for (int m = 0; m < 4; ++m) {
#pragma unroll
      for (int n = 0; n < 4; ++n) {
        int col = bn0 + wc * 64 + n * 16 + fr;
#pragma unroll
        for (int r = 0; r < 4; ++r) {
          int row = bm0 + wr * 64 + m * 16 + rq + r;
          C[(size_t)row * N + col] = f2bf(acc[m][n][r]);
        }
      }
    }
  }
}

// ---------------- windowed attention (MFMA, one wave per (b,h,window)) ----------------
#define PADV 24
#define PADP 24
__global__ __launch_bounds__(256) void win_attn(const unsigned short* __restrict__ qkv,
                                                unsigned short* __restrict__ aout) {
  __shared__ unsigned short lds[4][48 * PADV + 16 * PADP];
  const int tid = threadIdx.x;
  const int wave = tid >> 6, lane = tid & 63;
  const int wg = blockIdx.x * 4 + wave;     // ((b*1024 + w)*8 + h)
  const int h = wg & 7;
  const int bw = wg >> 3;
  const int w = bw & 1023, b = bw >> 10;
  const int wy = w >> 5, wx = w & 31;

  unsigned short* Vt = lds[wave];
  unsigned short* P  = lds[wave] + 48 * PADV;

  const int lg = lane >> 4;
  const int lr = lane & 15;

  const int n_lr = (wy * 4 + (lr >> 2)) * 128 + wx * 4 + (lr & 3);
  const size_t rowbase = ((size_t)(b * 16384 + n_lr)) * 1152 + h * 48;

  bf16x8 aq0, bk0;
  bf16x8 aq1 = {0, 0, 0, 0, 0, 0, 0, 0};
  bf16x8 bk1 = {0, 0, 0, 0, 0, 0, 0, 0};
  aq0 = *(const bf16x8*)(qkv + rowbase + lg * 8);
  bk0 = *(const bf16x8*)(qkv + rowbase + 384 + lg * 8);
  if (lg < 2) {
    aq1 = *(const bf16x8*)(qkv + rowbase + 32 + lg * 8);
    bk1 = *(const bf16x8*)(qkv + rowbase + 384 + 32 + lg * 8);
  }

  {
    bf16x8 v = *(const bf16x8*)(qkv + rowbase + 768 + lg * 8);
#pragma unroll
    for (int i = 0; i < 8; ++i) Vt[(lg * 8 + i) * PADV + lr] = (unsigned short)v[i];
    if (lane < 32) {
      bf16x8 v2 = *(const bf16x8*)(qkv + rowbase + 768 + 32 + lg * 8);
#pragma unroll
      for (int i = 0; i < 8; ++i) Vt[((4 + lg) * 8 + i) * PADV + lr] = (unsigned short)v2[i];
    }
  }

  f32x4 s = {0.f, 0.f, 0.f, 0.f};
  s = __builtin_amdgcn_mfma_f32_16x16x32_bf16(aq0, bk0, s, 0, 0, 0);
  s = __builtin_amdgcn_mfma_f32_16x16x32_bf16(aq1, bk1, s, 0, 0, 0);

  const float scale = 0.14433756729740643f;  // 1/sqrt(48)
  float p[4];
#pragma unroll
  for (int r = 0; r < 4; ++r) {
    float x = s[r] * scale;
    float m = x;
    m = fmaxf(m, __shfl_xor(m, 1));
    m = fmaxf(m, __shfl_xor(m, 2));
    m = fmaxf(m, __shfl_xor(m, 4));
    m = fmaxf(m, __shfl_xor(m, 8));
    float e = __expf(x - m);
    float t = e;
    t += __shfl_xor(t, 1);
    t += __shfl_xor(t, 2);
    t += __shfl_xor(t, 4);
    t += __shfl_xor(t, 8);
    p[r] = e / t;
  }
#pragma unroll
  for (int r = 0; r < 4; ++r) P[(lg * 4 + r) * PADP + lr] = f2bf(p[r]);

  __syncthreads();

  bf16x8 ap = {0, 0, 0, 0, 0, 0, 0, 0};
  if (lg < 2) ap = *(const bf16x8*)(P + lr * PADP + lg * 8);

  f32x4 o[3];
#pragma unroll
  for (int c = 0; c < 3; ++c) {
    bf16x8 bv = {0, 0, 0, 0, 0, 0, 0, 0};
    if (lg < 2) bv = *(const bf16x8*)(Vt + (c * 16 + lr) * PADV + lg * 8);
    f32x4 z = {0.f, 0.f, 0.f, 0.f};
    o[c] = __builtin_amdgcn_mfma_f32_16x16x32_bf16(ap, bv, z, 0, 0, 0);
  }

#pragma unroll
  for (int r = 0; r < 4; ++r) {
    const int qi = lg * 4 + r;
    const int nq = (wy * 4 + (qi >> 2)) * 128 + wx * 4 + (qi & 3);
    const size_t obase = ((size_t)(b * 16384 + nq)) * 384 + h * 48;
#pragma unroll
    for (int c = 0; c < 3; ++c)
      aout[obase + c * 16 + lr] = f2bf(o[c][r]);
  }
}

// ---------------- launch ----------------
extern "C" void kernel_launch(void* const* d_in, const int* in_sizes, int n_in,
                              void* d_out, int out_size, void* d_ws, size_t ws_size,
                              hipStream_t stream) {
  const float* x      = (const float*)d_in[0];
  const float* W_qkv  = (const float*)d_in[1];
  const float* W_proj = (const float*)d_in[2];
  const float* b_proj = (const float*)d_in[3];
  float* out = (float*)d_out;

  const int Bb = 8, Nn = 16384, Cc = 384;
  const int M = Bb * Nn;       // 131072
  const int threeC = 3 * Cc;   // 1152

  char* ws = (char*)d_ws;
  unsigned short* qkv_bf  = (unsigned short*)ws;                                   // M*1152 bf16
  unsigned short* xa_bf   = (unsigned short*)(ws + (size_t)M * threeC * 2);        // M*384  bf16
  unsigned short* wqkv_bf = (unsigned short*)(ws + (size_t)M * threeC * 2 + (size_t)M * Cc * 2);
  unsigned short* wproj_bf = wqkv_bf + threeC * Cc;

  conv_f32_bf16<<<2048, 256, 0, stream>>>((const float4*)x, (ushort4*)xa_bf, M * Cc / 4);
  conv_f32_bf16<<<432, 256, 0, stream>>>((const float4*)W_qkv, (ushort4*)wqkv_bf, threeC * Cc / 4);
  conv_f32_bf16<<<144, 256, 0, stream>>>((const float4*)W_proj, (ushort4*)wproj_bf, Cc * Cc / 4);

  // qkv = x @ W_qkv^T   (bf16 out): grid = 512 M-tiles x 9 N-tiles
  gemm_bt<0><<<(M / 256) * (threeC / 128), 512, 0, stream>>>(xa_bf, wqkv_bf, qkv_bf, nullptr,
                                                             M, threeC, Cc);

  win_attn<<<Bb * 8 * 1024 / 4, 256, 0, stream>>>(qkv_bf, xa_bf);

  // out = attn @ W_proj^T + b  (fp32 out): grid = 512 x 3
  gemm_bt<1><<<(M / 256) * (Cc / 128), 512, 0, stream>>>(xa_bf, wproj_bf, out, b_proj,
                                                         M, Cc, Cc);
}